// Round 2
// baseline (528.913 us; speedup 1.0000x reference)
//
#include <hip/hip_runtime.h>
#include <hip/hip_bf16.h>

// ParallelExperts: out = mean_e( relu(x@W1[e]+b1[e]) @ W2[e] + b2[e] ) @ Wf + bf
// Algebraic simplification: final linear applied once to the expert-mean:
//   out = (mean_e y_e) @ Wf + (mean_e b2) @ Wf-path folded via ybar.
//
// GEMMs: bf16 MFMA 16x16x32, m97 structure (128x128 tile, BK=32, 4 waves,
// global_load_lds 16B staging, A[M,K] x Bt[N,K]).
//
// Workspace is ADAPTIVE: token dimension processed in NC chunks so that
// fixed (82 MB) + (h+yal)/NC fits ws_size. NC chosen from ws_size only
// (constant across calls -> deterministic work).

#define D_IN  1024
#define D_HID 2048
#define D_OUT 1024
#define N_EXP 8
#define N_TOK 4096

typedef __attribute__((ext_vector_type(4))) float  f32x4;
typedef __attribute__((ext_vector_type(8))) short  s16x8;
typedef __attribute__((ext_vector_type(4))) short  s16x4;
typedef __attribute__((ext_vector_type(8))) __bf16 b16x8;

static __device__ __forceinline__ f32x4 mfma16x16x32(s16x8 a, s16x8 b, f32x4 c) {
  return __builtin_amdgcn_mfma_f32_16x16x32_bf16(
      __builtin_bit_cast(b16x8, a), __builtin_bit_cast(b16x8, b), c, 0, 0, 0);
}

#define GLDS16(gptr, lptr)                                                         \
  __builtin_amdgcn_global_load_lds(                                               \
      (const __attribute__((address_space(1))) void*)(gptr),                      \
      (__attribute__((address_space(3))) void*)(lptr), 16, 0, 0)

static __device__ __forceinline__ short f2b(float f) {
  return __builtin_bit_cast(short, __float2bfloat16(f));
}
static __device__ __forceinline__ float b2f(short s) {
  return __bfloat162float(__builtin_bit_cast(__hip_bfloat16, s));
}

// ---------------- prep kernels ----------------

__global__ void cast_x_kernel(const float* __restrict__ in, short* __restrict__ out, int n4) {
  int i = blockIdx.x * blockDim.x + threadIdx.x;
  if (i >= n4) return;
  f32x4 v = ((const f32x4*)in)[i];
  s16x4 o;
  o[0] = f2b(v[0]); o[1] = f2b(v[1]); o[2] = f2b(v[2]); o[3] = f2b(v[3]);
  ((s16x4*)out)[i] = o;
}

// in: [R][C] f32 (slab z), out: [C][R] bf16 (slab z)
__global__ void tcast_kernel(const float* __restrict__ in, short* __restrict__ out, int R, int C) {
  __shared__ float t[32][33];
  size_t slab = (size_t)blockIdx.z * R * C;
  const float* src = in + slab;
  short* dst = out + slab;
  int c0 = blockIdx.x * 32, r0 = blockIdx.y * 32;
  int tx = threadIdx.x, ty = threadIdx.y;
#pragma unroll
  for (int i = 0; i < 32; i += 8)
    t[ty + i][tx] = src[(size_t)(r0 + ty + i) * C + c0 + tx];
  __syncthreads();
#pragma unroll
  for (int i = 0; i < 32; i += 8)
    dst[(size_t)(c0 + ty + i) * R + r0 + tx] = f2b(t[tx][ty + i]);
}

__global__ void b2mean_kernel(const float* __restrict__ b2, float* __restrict__ b2m) {
  int o = blockIdx.x * blockDim.x + threadIdx.x;
  if (o < D_OUT) {
    float s = 0.f;
#pragma unroll
    for (int e = 0; e < N_EXP; ++e) s += b2[e * D_OUT + o];
    b2m[o] = s * 0.125f;
  }
}

// ---------------- GEMM (m97 structure) ----------------
// C[M,N] = A[M,K] * Bt[N,K]^T (+bias[col]) (+relu), per blockIdx.z slab.

template <bool RELU, bool OUTBF16>
__global__ __launch_bounds__(256) void gemm_bt_kernel(
    const short* __restrict__ A, const short* __restrict__ Bt, void* __restrict__ C,
    const float* __restrict__ bias, int K, int ldc,
    long sAe, long sBe, long sCe, long sBiasE) {
  constexpr int BM = 128, BN = 128, BK = 32;
  __shared__ short As[BM * BK];
  __shared__ short Bs[BN * BK];
  const int tid  = threadIdx.x;
  const int wid  = tid >> 6;
  const int lane = tid & 63;
  const int e    = blockIdx.z;

  const short* Ap = A + (size_t)e * sAe + (size_t)blockIdx.y * BM * K;
  const short* Bp = Bt + (size_t)e * sBe + (size_t)blockIdx.x * BN * K;

  // staging: round r (0/1), wave w fills LDS elems [r*2048 + w*512, +512)
  // lane i covers row r*64 + w*16 + (i>>2), k-cols (i&3)*8 .. +7
  const int srow = wid * 16 + (lane >> 2);
  const int scol = (lane & 3) * 8;

  const int wm = (wid >> 1) * 64, wn = (wid & 1) * 64;
  const int lr = lane & 15, lk = (lane >> 4) * 8;

  f32x4 acc[4][4] = {};

  const int nkt = K / BK;
  for (int kt = 0; kt < nkt; ++kt) {
    __syncthreads();  // previous iter's ds_reads done before overwrite
    const size_t ko = (size_t)kt * BK;
    GLDS16(Ap + (size_t)srow * K + ko + scol,        &As[wid * 512]);
    GLDS16(Ap + (size_t)(srow + 64) * K + ko + scol, &As[2048 + wid * 512]);
    GLDS16(Bp + (size_t)srow * K + ko + scol,        &Bs[wid * 512]);
    GLDS16(Bp + (size_t)(srow + 64) * K + ko + scol, &Bs[2048 + wid * 512]);
    __syncthreads();  // staging visible (compiler drains vmcnt before barrier)

    s16x8 a[4], b[4];
#pragma unroll
    for (int mi = 0; mi < 4; ++mi)
      a[mi] = *(const s16x8*)&As[(wm + mi * 16 + lr) * BK + lk];
#pragma unroll
    for (int ni = 0; ni < 4; ++ni)
      b[ni] = *(const s16x8*)&Bs[(wn + ni * 16 + lr) * BK + lk];
#pragma unroll
    for (int mi = 0; mi < 4; ++mi)
#pragma unroll
      for (int ni = 0; ni < 4; ++ni)
        acc[mi][ni] = mfma16x16x32(a[mi], b[ni], acc[mi][ni]);
  }

  // epilogue: D lane mapping col=lane&15, row=(lane>>4)*4+j
  const size_t Cbase = (size_t)e * sCe;
  const int row0 = blockIdx.y * BM + wm + (lane >> 4) * 4;
  const int col0 = blockIdx.x * BN + wn + lr;
#pragma unroll
  for (int ni = 0; ni < 4; ++ni) {
    const int col = col0 + ni * 16;
    const float bv = bias ? bias[(size_t)e * sBiasE + col] : 0.f;
#pragma unroll
    for (int mi = 0; mi < 4; ++mi) {
#pragma unroll
      for (int j = 0; j < 4; ++j) {
        float v = acc[mi][ni][j] + bv;
        if (RELU) v = v > 0.f ? v : 0.f;
        const size_t idx = Cbase + (size_t)(row0 + mi * 16 + j) * ldc + col;
        if (OUTBF16) ((short*)C)[idx] = f2b(v);
        else         ((float*)C)[idx] = v;
      }
    }
  }
}

// ---------------- reduce over experts (per token-chunk) ----------------
// yal: [E][ntokc][D_OUT] bf16; ybar_chunk = mean_e yal + b2m (bf16)

__global__ void reduce_y_kernel(const short* __restrict__ yal, const float* __restrict__ b2m,
                                short* __restrict__ ybar, long slab, long total) {
  const size_t base = ((size_t)blockIdx.x * blockDim.x + threadIdx.x) * 8;
  if (base >= (size_t)total) return;
  float s[8] = {};
#pragma unroll
  for (int e = 0; e < N_EXP; ++e) {
    s16x8 v = *(const s16x8*)&yal[(size_t)e * slab + base];
#pragma unroll
    for (int j = 0; j < 8; ++j) s[j] += b2f(v[j]);
  }
  const int col = (int)(base & (D_OUT - 1));
  s16x8 o;
#pragma unroll
  for (int j = 0; j < 8; ++j) o[j] = f2b(s[j] * 0.125f + b2m[col + j]);
  *(s16x8*)&ybar[base] = o;
}

__global__ void tail_kernel(float* __restrict__ out, int from, int n) {
  int i = from + blockIdx.x * blockDim.x + threadIdx.x;
  if (i < n) out[i] = 0.f;
}

// ---------------- launch ----------------

extern "C" void kernel_launch(void* const* d_in, const int* in_sizes, int n_in,
                              void* d_out, int out_size, void* d_ws, size_t ws_size,
                              hipStream_t stream) {
  const float* x  = (const float*)d_in[0];
  const float* W1 = (const float*)d_in[1];
  const float* b1 = (const float*)d_in[2];
  const float* W2 = (const float*)d_in[3];
  const float* b2 = (const float*)d_in[4];
  const float* Wf = (const float*)d_in[5];
  const float* bf = (const float*)d_in[6];
  float* out = (float*)d_out;

  // ---- adaptive chunking: fit fixed + (h+yal)/NC into ws_size ----
  const size_t sz_xb  = (size_t)N_TOK * D_IN * 2;
  const size_t sz_W1t = (size_t)N_EXP * D_HID * D_IN * 2;
  const size_t sz_W2t = (size_t)N_EXP * D_OUT * D_HID * 2;
  const size_t sz_Wft = (size_t)D_OUT * D_OUT * 2;
  const size_t sz_b2m = (size_t)D_OUT * 4;
  const size_t sz_ybr = (size_t)N_TOK * D_OUT * 2;
  const size_t fixed  = sz_xb + sz_W1t + sz_W2t + sz_Wft + sz_b2m + sz_ybr;
  const size_t per_full = (size_t)N_EXP * N_TOK * D_HID * 2   // h
                        + (size_t)N_EXP * N_TOK * D_OUT * 2;  // yal
  int NC = 16;
  for (int c = 1; c <= 8; c <<= 1) {
    if (fixed + per_full / c <= ws_size) { NC = c; break; }
  }
  const int ntokc = N_TOK / NC;

  char* ws = (char*)d_ws;
  short* xb  = (short*)ws; ws += sz_xb;
  short* W1t = (short*)ws; ws += sz_W1t;
  short* W2t = (short*)ws; ws += sz_W2t;
  short* Wft = (short*)ws; ws += sz_Wft;
  float* b2m = (float*)ws; ws += sz_b2m;
  short* ybr = (short*)ws; ws += sz_ybr;
  short* h   = (short*)ws; ws += (size_t)N_EXP * ntokc * D_HID * 2;
  short* yal = (short*)ws;

  // ---- prep: casts + transposes ----
  hipLaunchKernelGGL(cast_x_kernel, dim3(N_TOK * D_IN / 4 / 256), dim3(256), 0, stream,
                     x, xb, N_TOK * D_IN / 4);
  hipLaunchKernelGGL(tcast_kernel, dim3(D_HID / 32, D_IN / 32, N_EXP), dim3(32, 8), 0, stream,
                     W1, W1t, D_IN, D_HID);
  hipLaunchKernelGGL(tcast_kernel, dim3(D_OUT / 32, D_HID / 32, N_EXP), dim3(32, 8), 0, stream,
                     W2, W2t, D_HID, D_OUT);
  hipLaunchKernelGGL(tcast_kernel, dim3(D_OUT / 32, D_OUT / 32, 1), dim3(32, 8), 0, stream,
                     Wf, Wft, D_OUT, D_OUT);
  hipLaunchKernelGGL(b2mean_kernel, dim3(4), dim3(256), 0, stream, b2, b2m);

  // ---- per-token-chunk: GEMM1 -> GEMM2 -> expert-mean ----
  for (int c = 0; c < NC; ++c) {
    const short* xc = xb + (size_t)c * ntokc * D_IN;
    short* ybc = ybr + (size_t)c * ntokc * D_OUT;

    // h[e] = relu(xc @ W1[e] + b1[e])   [ntokc, D_HID] per e
    hipLaunchKernelGGL((gemm_bt_kernel<true, true>),
                       dim3(D_HID / 128, ntokc / 128, N_EXP), dim3(256), 0, stream,
                       xc, W1t, (void*)h, b1, D_IN, D_HID,
                       0L, (long)D_HID * D_IN, (long)ntokc * D_HID, (long)D_HID);

    // yal[e] = h[e] @ W2[e]   [ntokc, D_OUT] per e (bias folded into reduce)
    hipLaunchKernelGGL((gemm_bt_kernel<false, true>),
                       dim3(D_OUT / 128, ntokc / 128, N_EXP), dim3(256), 0, stream,
                       h, W2t, (void*)yal, (const float*)nullptr, D_HID, D_OUT,
                       (long)ntokc * D_HID, (long)D_OUT * D_HID, (long)ntokc * D_OUT, 0L);

    // ybc = mean_e yal + mean_e b2
    hipLaunchKernelGGL(reduce_y_kernel, dim3(ntokc * D_OUT / 8 / 256), dim3(256), 0, stream,
                       yal, b2m, ybc, (long)ntokc * D_OUT, (long)ntokc * D_OUT);
  }

  // ---- out = ybar @ Wf + bf  (fp32 out) ----
  hipLaunchKernelGGL((gemm_bt_kernel<false, false>),
                     dim3(D_OUT / 128, N_TOK / 128, 1), dim3(256), 0, stream,
                     ybr, Wft, d_out, bf, D_OUT, D_OUT, 0L, 0L, 0L, 0L);

  // ---- second (scalar) output = 0 ----
  int tail = out_size - N_TOK * D_OUT;
  if (tail > 0)
    hipLaunchKernelGGL(tail_kernel, dim3((tail + 63) / 64), dim3(64), 0, stream,
                       out, N_TOK * D_OUT, out_size);
}

// Round 3
// 422.446 us; speedup vs baseline: 1.2520x; 1.2520x over previous
//
#include <hip/hip_runtime.h>
#include <hip/hip_bf16.h>

// ParallelExperts: out = mean_e( relu(x@W1[e]+b1[e]) @ W2[e] + b2[e] ) @ Wf + bf
// Final linear folded past the expert-mean (one GEMM3 on ybar).
//
// GEMM1/GEMM2: 256x256 tile, BK=64, 8 waves, double-buffered LDS (128 KiB),
// T3 "minimum 2-phase" schedule: STAGE(t+1) issued before compute(t), one
// barrier per K-step (compiler drains vmcnt+lgkm at the barrier).
// GEMM3 (small, 8.6 GF): verified 128x128 m97-structure kernel.

#define D_IN  1024
#define D_HID 2048
#define D_OUT 1024
#define N_EXP 8
#define N_TOK 4096

typedef __attribute__((ext_vector_type(4))) float  f32x4;
typedef __attribute__((ext_vector_type(8))) short  s16x8;
typedef __attribute__((ext_vector_type(4))) short  s16x4;
typedef __attribute__((ext_vector_type(8))) __bf16 b16x8;

static __device__ __forceinline__ f32x4 mfma16x16x32(s16x8 a, s16x8 b, f32x4 c) {
  return __builtin_amdgcn_mfma_f32_16x16x32_bf16(
      __builtin_bit_cast(b16x8, a), __builtin_bit_cast(b16x8, b), c, 0, 0, 0);
}

#define GLDS16(gptr, lptr)                                                         \
  __builtin_amdgcn_global_load_lds(                                               \
      (const __attribute__((address_space(1))) void*)(gptr),                      \
      (__attribute__((address_space(3))) void*)(lptr), 16, 0, 0)

static __device__ __forceinline__ short f2b(float f) {
  return __builtin_bit_cast(short, __float2bfloat16(f));
}
static __device__ __forceinline__ float b2f(short s) {
  return __bfloat162float(__builtin_bit_cast(__hip_bfloat16, s));
}

// ---------------- prep kernels ----------------

__global__ void cast_x_kernel(const float* __restrict__ in, short* __restrict__ out, int n4) {
  int i = blockIdx.x * blockDim.x + threadIdx.x;
  if (i >= n4) return;
  f32x4 v = ((const f32x4*)in)[i];
  s16x4 o;
  o[0] = f2b(v[0]); o[1] = f2b(v[1]); o[2] = f2b(v[2]); o[3] = f2b(v[3]);
  ((s16x4*)out)[i] = o;
}

// in: [R][C] f32 (slab z), out: [C][R] bf16 (slab z)
__global__ void tcast_kernel(const float* __restrict__ in, short* __restrict__ out, int R, int C) {
  __shared__ float t[32][33];
  size_t slab = (size_t)blockIdx.z * R * C;
  const float* src = in + slab;
  short* dst = out + slab;
  int c0 = blockIdx.x * 32, r0 = blockIdx.y * 32;
  int tx = threadIdx.x, ty = threadIdx.y;
#pragma unroll
  for (int i = 0; i < 32; i += 8)
    t[ty + i][tx] = src[(size_t)(r0 + ty + i) * C + c0 + tx];
  __syncthreads();
#pragma unroll
  for (int i = 0; i < 32; i += 8)
    dst[(size_t)(c0 + ty + i) * R + r0 + tx] = f2b(t[tx][ty + i]);
}

__global__ void b2mean_kernel(const float* __restrict__ b2, float* __restrict__ b2m) {
  int o = blockIdx.x * blockDim.x + threadIdx.x;
  if (o < D_OUT) {
    float s = 0.f;
#pragma unroll
    for (int e = 0; e < N_EXP; ++e) s += b2[e * D_OUT + o];
    b2m[o] = s * 0.125f;
  }
}

// ---------------- 256x256 2-phase GEMM ----------------
// C[M,N] = A[M,K] * Bt[N,K]^T (+bias[col]) (+relu), per blockIdx.z slab.
// 8 waves (2M x 4N), per-wave 128x64 output, BK=64, dbuf LDS 128 KiB.

static __device__ __forceinline__ void stage_tile256(
    const short* __restrict__ Ab, const short* __restrict__ Bb, int K, size_t ko,
    short* slotA, short* slotB, int wid, int gr, int gcol) {
  // wave-uniform LDS dest (+lane*16B appended by HW); per-lane global src.
#pragma unroll
  for (int r = 0; r < 4; ++r)
    GLDS16(Ab + (size_t)(r * 64 + wid * 8 + gr) * K + ko + gcol,
           slotA + (r * 64 + wid * 8) * 64);
#pragma unroll
  for (int r = 0; r < 4; ++r)
    GLDS16(Bb + (size_t)(r * 64 + wid * 8 + gr) * K + ko + gcol,
           slotB + (r * 64 + wid * 8) * 64);
}

template <bool RELU, bool OUTBF16>
__global__ __launch_bounds__(512) void gemm256_bt_kernel(
    const short* __restrict__ A, const short* __restrict__ Bt, void* __restrict__ C,
    const float* __restrict__ bias, int K, int ldc,
    long sAe, long sBe, long sCe, long sBiasE) {
  constexpr int BM = 256, BN = 256, BK = 64;
  constexpr int SLOT = BM * BK;          // 16384 shorts = 32 KiB
  extern __shared__ short lds[];         // [buf(2)][A,B] -> 128 KiB

  const int tid  = threadIdx.x;
  const int wid  = tid >> 6;
  const int lane = tid & 63;
  const int e    = blockIdx.z;

  const short* Ab = A + (size_t)e * sAe + (size_t)blockIdx.y * BM * K;
  const short* Bb = Bt + (size_t)e * sBe + (size_t)blockIdx.x * BN * K;

  const int gr = lane >> 3, gcol = (lane & 7) * 8;  // staging lane geometry
  const int wm = wid >> 2, wn = wid & 3;            // 2M x 4N wave grid
  const int lr = lane & 15, lk = (lane >> 4) * 8;   // fragment lane geometry

  f32x4 acc[8][4] = {};
  const int nkt = K / BK;

  // prologue: stage tile 0 into buf0; barrier drains vmcnt
  stage_tile256(Ab, Bb, K, 0, lds, lds + SLOT, wid, gr, gcol);
  __syncthreads();

  for (int kt = 0; kt < nkt; ++kt) {
    const int cur = kt & 1;
    short* curbase = lds + cur * (2 * SLOT);
    short* nxtbase = lds + (cur ^ 1) * (2 * SLOT);

    // phase A: issue next tile's staging (overlaps with compute below)
    if (kt + 1 < nkt)
      stage_tile256(Ab, Bb, K, (size_t)(kt + 1) * BK, nxtbase, nxtbase + SLOT,
                    wid, gr, gcol);

    // phase B: ds_read fragments + MFMA on current buffer
    const short* As_ = curbase;
    const short* Bs_ = curbase + SLOT;
#pragma unroll
    for (int ks = 0; ks < 2; ++ks) {
      s16x8 av[8], bv[4];
#pragma unroll
      for (int mi = 0; mi < 8; ++mi)
        av[mi] = *(const s16x8*)&As_[(wm * 128 + mi * 16 + lr) * BK + ks * 32 + lk];
#pragma unroll
      for (int ni = 0; ni < 4; ++ni)
        bv[ni] = *(const s16x8*)&Bs_[(wn * 64 + ni * 16 + lr) * BK + ks * 32 + lk];
#pragma unroll
      for (int mi = 0; mi < 8; ++mi)
#pragma unroll
        for (int ni = 0; ni < 4; ++ni)
          acc[mi][ni] = mfma16x16x32(av[mi], bv[ni], acc[mi][ni]);
    }
    // one barrier per K-step: drains vmcnt (next stage complete) and ensures
    // all waves finished reading cur before it is restaged next iteration.
    __syncthreads();
  }

  // epilogue: D mapping col=lane&15, row=(lane>>4)*4+j
  const size_t Cbase = (size_t)e * sCe;
  const int row0 = blockIdx.y * BM + wm * 128 + (lane >> 4) * 4;
  const int col0 = blockIdx.x * BN + wn * 64 + lr;
#pragma unroll
  for (int ni = 0; ni < 4; ++ni) {
    const int col = col0 + ni * 16;
    const float bvv = bias ? bias[(size_t)e * sBiasE + col] : 0.f;
#pragma unroll
    for (int mi = 0; mi < 8; ++mi) {
#pragma unroll
      for (int j = 0; j < 4; ++j) {
        float v = acc[mi][ni][j] + bvv;
        if (RELU) v = v > 0.f ? v : 0.f;
        const size_t idx = Cbase + (size_t)(row0 + mi * 16 + j) * ldc + col;
        if (OUTBF16) ((short*)C)[idx] = f2b(v);
        else         ((float*)C)[idx] = v;
      }
    }
  }
}

// ---------------- 128x128 m97 GEMM (kept for GEMM3) ----------------

template <bool RELU, bool OUTBF16>
__global__ __launch_bounds__(256) void gemm_bt_kernel(
    const short* __restrict__ A, const short* __restrict__ Bt, void* __restrict__ C,
    const float* __restrict__ bias, int K, int ldc,
    long sAe, long sBe, long sCe, long sBiasE) {
  constexpr int BM = 128, BN = 128, BK = 32;
  __shared__ short As[BM * BK];
  __shared__ short Bs[BN * BK];
  const int tid  = threadIdx.x;
  const int wid  = tid >> 6;
  const int lane = tid & 63;
  const int e    = blockIdx.z;

  const short* Ap = A + (size_t)e * sAe + (size_t)blockIdx.y * BM * K;
  const short* Bp = Bt + (size_t)e * sBe + (size_t)blockIdx.x * BN * K;

  const int srow = wid * 16 + (lane >> 2);
  const int scol = (lane & 3) * 8;
  const int wm = (wid >> 1) * 64, wn = (wid & 1) * 64;
  const int lr = lane & 15, lk = (lane >> 4) * 8;

  f32x4 acc[4][4] = {};
  const int nkt = K / BK;
  for (int kt = 0; kt < nkt; ++kt) {
    __syncthreads();
    const size_t ko = (size_t)kt * BK;
    GLDS16(Ap + (size_t)srow * K + ko + scol,        &As[wid * 512]);
    GLDS16(Ap + (size_t)(srow + 64) * K + ko + scol, &As[2048 + wid * 512]);
    GLDS16(Bp + (size_t)srow * K + ko + scol,        &Bs[wid * 512]);
    GLDS16(Bp + (size_t)(srow + 64) * K + ko + scol, &Bs[2048 + wid * 512]);
    __syncthreads();

    s16x8 a[4], b[4];
#pragma unroll
    for (int mi = 0; mi < 4; ++mi)
      a[mi] = *(const s16x8*)&As[(wm + mi * 16 + lr) * BK + lk];
#pragma unroll
    for (int ni = 0; ni < 4; ++ni)
      b[ni] = *(const s16x8*)&Bs[(wn + ni * 16 + lr) * BK + lk];
#pragma unroll
    for (int mi = 0; mi < 4; ++mi)
#pragma unroll
      for (int ni = 0; ni < 4; ++ni)
        acc[mi][ni] = mfma16x16x32(a[mi], b[ni], acc[mi][ni]);
  }

  const size_t Cbase = (size_t)e * sCe;
  const int row0 = blockIdx.y * BM + wm + (lane >> 4) * 4;
  const int col0 = blockIdx.x * BN + wn + lr;
#pragma unroll
  for (int ni = 0; ni < 4; ++ni) {
    const int col = col0 + ni * 16;
    const float bv = bias ? bias[(size_t)e * sBiasE + col] : 0.f;
#pragma unroll
    for (int mi = 0; mi < 4; ++mi) {
#pragma unroll
      for (int j = 0; j < 4; ++j) {
        float v = acc[mi][ni][j] + bv;
        if (RELU) v = v > 0.f ? v : 0.f;
        const size_t idx = Cbase + (size_t)(row0 + mi * 16 + j) * ldc + col;
        if (OUTBF16) ((short*)C)[idx] = f2b(v);
        else         ((float*)C)[idx] = v;
      }
    }
  }
}

// ---------------- reduce over experts (per token-chunk) ----------------

__global__ void reduce_y_kernel(const short* __restrict__ yal, const float* __restrict__ b2m,
                                short* __restrict__ ybar, long slab, long total) {
  const size_t base = ((size_t)blockIdx.x * blockDim.x + threadIdx.x) * 8;
  if (base >= (size_t)total) return;
  float s[8] = {};
#pragma unroll
  for (int e = 0; e < N_EXP; ++e) {
    s16x8 v = *(const s16x8*)&yal[(size_t)e * slab + base];
#pragma unroll
    for (int j = 0; j < 8; ++j) s[j] += b2f(v[j]);
  }
  const int col = (int)(base & (D_OUT - 1));
  s16x8 o;
#pragma unroll
  for (int j = 0; j < 8; ++j) o[j] = f2b(s[j] * 0.125f + b2m[col + j]);
  *(s16x8*)&ybar[base] = o;
}

__global__ void tail_kernel(float* __restrict__ out, int from, int n) {
  int i = from + blockIdx.x * blockDim.x + threadIdx.x;
  if (i < n) out[i] = 0.f;
}

// ---------------- launch ----------------

extern "C" void kernel_launch(void* const* d_in, const int* in_sizes, int n_in,
                              void* d_out, int out_size, void* d_ws, size_t ws_size,
                              hipStream_t stream) {
  const float* x  = (const float*)d_in[0];
  const float* W1 = (const float*)d_in[1];
  const float* b1 = (const float*)d_in[2];
  const float* W2 = (const float*)d_in[3];
  const float* b2 = (const float*)d_in[4];
  const float* Wf = (const float*)d_in[5];
  const float* bf = (const float*)d_in[6];
  float* out = (float*)d_out;

  // ---- adaptive chunking: fit fixed + (h+yal)/NC into ws_size ----
  const size_t sz_xb  = (size_t)N_TOK * D_IN * 2;
  const size_t sz_W1t = (size_t)N_EXP * D_HID * D_IN * 2;
  const size_t sz_W2t = (size_t)N_EXP * D_OUT * D_HID * 2;
  const size_t sz_Wft = (size_t)D_OUT * D_OUT * 2;
  const size_t sz_b2m = (size_t)D_OUT * 4;
  const size_t sz_ybr = (size_t)N_TOK * D_OUT * 2;
  const size_t fixed  = sz_xb + sz_W1t + sz_W2t + sz_Wft + sz_b2m + sz_ybr;
  const size_t per_full = (size_t)N_EXP * N_TOK * D_HID * 2   // h
                        + (size_t)N_EXP * N_TOK * D_OUT * 2;  // yal
  int NC = 16;
  for (int c = 1; c <= 8; c <<= 1) {
    if (fixed + per_full / c <= ws_size) { NC = c; break; }
  }
  const int ntokc = N_TOK / NC;

  char* ws = (char*)d_ws;
  short* xb  = (short*)ws; ws += sz_xb;
  short* W1t = (short*)ws; ws += sz_W1t;
  short* W2t = (short*)ws; ws += sz_W2t;
  short* Wft = (short*)ws; ws += sz_Wft;
  float* b2m = (float*)ws; ws += sz_b2m;
  short* ybr = (short*)ws; ws += sz_ybr;
  short* h   = (short*)ws; ws += (size_t)N_EXP * ntokc * D_HID * 2;
  short* yal = (short*)ws;

  // ---- prep: casts + transposes ----
  hipLaunchKernelGGL(cast_x_kernel, dim3(N_TOK * D_IN / 4 / 256), dim3(256), 0, stream,
                     x, xb, N_TOK * D_IN / 4);
  hipLaunchKernelGGL(tcast_kernel, dim3(D_HID / 32, D_IN / 32, N_EXP), dim3(32, 8), 0, stream,
                     W1, W1t, D_IN, D_HID);
  hipLaunchKernelGGL(tcast_kernel, dim3(D_OUT / 32, D_HID / 32, N_EXP), dim3(32, 8), 0, stream,
                     W2, W2t, D_HID, D_OUT);
  hipLaunchKernelGGL(tcast_kernel, dim3(D_OUT / 32, D_OUT / 32, 1), dim3(32, 8), 0, stream,
                     Wf, Wft, D_OUT, D_OUT);
  hipLaunchKernelGGL(b2mean_kernel, dim3(4), dim3(256), 0, stream, b2, b2m);

  const size_t ldsz = 131072;  // 128 KiB dbuf LDS

  // ---- per-token-chunk: GEMM1 -> GEMM2 -> expert-mean ----
  for (int c = 0; c < NC; ++c) {
    const short* xc = xb + (size_t)c * ntokc * D_IN;
    short* ybc = ybr + (size_t)c * ntokc * D_OUT;

    // h[e] = relu(xc @ W1[e] + b1[e])   [ntokc, D_HID] per e
    hipLaunchKernelGGL((gemm256_bt_kernel<true, true>),
                       dim3(D_HID / 256, ntokc / 256, N_EXP), dim3(512), ldsz, stream,
                       xc, W1t, (void*)h, b1, D_IN, D_HID,
                       0L, (long)D_HID * D_IN, (long)ntokc * D_HID, (long)D_HID);

    // yal[e] = h[e] @ W2[e]   [ntokc, D_OUT] per e (bias folded into reduce)
    hipLaunchKernelGGL((gemm256_bt_kernel<false, true>),
                       dim3(D_OUT / 256, ntokc / 256, N_EXP), dim3(512), ldsz, stream,
                       h, W2t, (void*)yal, (const float*)nullptr, D_HID, D_OUT,
                       (long)ntokc * D_HID, (long)D_OUT * D_HID, (long)ntokc * D_OUT, 0L);

    // ybc = mean_e yal + mean_e b2
    hipLaunchKernelGGL(reduce_y_kernel, dim3(ntokc * D_OUT / 8 / 256), dim3(256), 0, stream,
                       yal, b2m, ybc, (long)ntokc * D_OUT, (long)ntokc * D_OUT);
  }

  // ---- out = ybar @ Wf + bf  (fp32 out), 128^2 kernel ----
  hipLaunchKernelGGL((gemm_bt_kernel<false, false>),
                     dim3(D_OUT / 128, N_TOK / 128, 1), dim3(256), 0, stream,
                     ybr, Wft, d_out, bf, D_OUT, D_OUT, 0L, 0L, 0L, 0L);

  // ---- second (scalar) output = 0 ----
  int tail = out_size - N_TOK * D_OUT;
  if (tail > 0)
    hipLaunchKernelGGL(tail_kernel, dim3((tail + 63) / 64), dim3(64), 0, stream,
                       out, N_TOK * D_OUT, out_size);
}

// Round 4
// 413.730 us; speedup vs baseline: 1.2784x; 1.0211x over previous
//
#include <hip/hip_runtime.h>
#include <hip/hip_bf16.h>

// ParallelExperts: out = mean_e( relu(x@W1[e]+b1[e]) @ W2[e] + b2[e] ) @ Wf + bf
// Final linear folded past the expert-mean (one GEMM3 on ybar).
//
// GEMM1/GEMM2: 256x256 tile, BK=32, 8 waves, 4-slot LDS ring (128 KiB),
// counted-vmcnt software pipeline (T4): stage tile t+3 while computing t,
// wait vmcnt(8) (= tiles t+1,t+2 in flight) + raw s_barrier per K-step.
// [256][32] LDS rows (64B) put fragment reads at the LDS bank floor.
// GEMM3 (small, 8.6 GF): verified 128x128 m97-structure kernel.

#define D_IN  1024
#define D_HID 2048
#define D_OUT 1024
#define N_EXP 8
#define N_TOK 4096

typedef __attribute__((ext_vector_type(4))) float  f32x4;
typedef __attribute__((ext_vector_type(8))) short  s16x8;
typedef __attribute__((ext_vector_type(4))) short  s16x4;
typedef __attribute__((ext_vector_type(8))) __bf16 b16x8;

static __device__ __forceinline__ f32x4 mfma16x16x32(s16x8 a, s16x8 b, f32x4 c) {
  return __builtin_amdgcn_mfma_f32_16x16x32_bf16(
      __builtin_bit_cast(b16x8, a), __builtin_bit_cast(b16x8, b), c, 0, 0, 0);
}

#define GLDS16(gptr, lptr)                                                         \
  __builtin_amdgcn_global_load_lds(                                               \
      (const __attribute__((address_space(1))) void*)(gptr),                      \
      (__attribute__((address_space(3))) void*)(lptr), 16, 0, 0)

#define WAITV(n) asm volatile("s_waitcnt vmcnt(" #n ")" ::: "memory")
#define SBAR()                                                                     \
  do {                                                                             \
    __builtin_amdgcn_sched_barrier(0);                                             \
    __builtin_amdgcn_s_barrier();                                                  \
    __builtin_amdgcn_sched_barrier(0);                                             \
  } while (0)

static __device__ __forceinline__ short f2b(float f) {
  return __builtin_bit_cast(short, __float2bfloat16(f));
}
static __device__ __forceinline__ float b2f(short s) {
  return __bfloat162float(__builtin_bit_cast(__hip_bfloat16, s));
}

// ---------------- prep kernels ----------------

__global__ void cast_x_kernel(const float* __restrict__ in, short* __restrict__ out, int n4) {
  int i = blockIdx.x * blockDim.x + threadIdx.x;
  if (i >= n4) return;
  f32x4 v = ((const f32x4*)in)[i];
  s16x4 o;
  o[0] = f2b(v[0]); o[1] = f2b(v[1]); o[2] = f2b(v[2]); o[3] = f2b(v[3]);
  ((s16x4*)out)[i] = o;
}

// in: [R][C] f32 (slab z), out: [C][R] bf16 (slab z)
__global__ void tcast_kernel(const float* __restrict__ in, short* __restrict__ out, int R, int C) {
  __shared__ float t[32][33];
  size_t slab = (size_t)blockIdx.z * R * C;
  const float* src = in + slab;
  short* dst = out + slab;
  int c0 = blockIdx.x * 32, r0 = blockIdx.y * 32;
  int tx = threadIdx.x, ty = threadIdx.y;
#pragma unroll
  for (int i = 0; i < 32; i += 8)
    t[ty + i][tx] = src[(size_t)(r0 + ty + i) * C + c0 + tx];
  __syncthreads();
#pragma unroll
  for (int i = 0; i < 32; i += 8)
    dst[(size_t)(c0 + ty + i) * R + r0 + tx] = f2b(t[tx][ty + i]);
}

__global__ void b2mean_kernel(const float* __restrict__ b2, float* __restrict__ b2m) {
  int o = blockIdx.x * blockDim.x + threadIdx.x;
  if (o < D_OUT) {
    float s = 0.f;
#pragma unroll
    for (int e = 0; e < N_EXP; ++e) s += b2[e * D_OUT + o];
    b2m[o] = s * 0.125f;
  }
}

// ---------------- 256x256 ring-4 GEMM ----------------
// C[M,N] = A[M,K] * Bt[N,K]^T (+bias[col]) (+relu), per blockIdx.z slab.
// 8 waves (2M x 4N), per-wave 128x64 output, BK=32, 4-slot LDS ring.

template <bool RELU, bool OUTBF16>
__global__ __launch_bounds__(512) void gemm256_ring_kernel(
    const short* __restrict__ A, const short* __restrict__ Bt, void* __restrict__ C,
    const float* __restrict__ bias, int K, int ldc,
    long sAe, long sBe, long sCe, long sBiasE) {
  constexpr int BM = 256, BN = 256, BK = 32;
  constexpr int SLOT = 16384;            // shorts per ring slot: A 8192 + B 8192 (32 KiB)
  extern __shared__ short lds[];         // 4 slots = 128 KiB

  const int tid  = threadIdx.x;
  const int wid  = tid >> 6;
  const int lane = tid & 63;
  const int e    = blockIdx.z;

  const short* Ab = A + (size_t)e * sAe + (size_t)blockIdx.y * BM * K;
  const short* Bb = Bt + (size_t)e * sBe + (size_t)blockIdx.x * BN * K;

  // staging: region r covers rows r*128..+127; wave wid covers 16 rows,
  // lane -> (row = wid*16 + lane>>2, colel = (lane&3)*8). LDS dest is
  // wave-uniform (+lane*16B appended by HW) and matches [row][32] linear.
  const int strow = wid * 16 + (lane >> 2);
  const int stcol = (lane & 3) * 8;

  const int wm = wid >> 2, wn = wid & 3;            // 2M x 4N wave grid
  const int lr = lane & 15, lk = (lane >> 4) * 8;   // fragment lane geometry

  f32x4 acc[8][4] = {};
  const int nkt = K / BK;  // >= 32 for all our shapes

  auto STAGE = [&](int t) {
    short* slot = lds + (size_t)(t & 3) * SLOT;
    const size_t ko = (size_t)t * BK;
#pragma unroll
    for (int r = 0; r < 2; ++r) {
      GLDS16(Ab + (size_t)(r * 128 + strow) * K + ko + stcol,
             slot + r * 4096 + wid * 512);
      GLDS16(Bb + (size_t)(r * 128 + strow) * K + ko + stcol,
             slot + 8192 + r * 4096 + wid * 512);
    }
  };

  auto COMPUTE = [&](int t) {
    const short* As_ = lds + (size_t)(t & 3) * SLOT;
    const short* Bs_ = As_ + 8192;
    s16x8 av[8], bv[4];
#pragma unroll
    for (int mi = 0; mi < 8; ++mi)
      av[mi] = *(const s16x8*)&As_[(wm * 128 + mi * 16 + lr) * BK + lk];
#pragma unroll
    for (int ni = 0; ni < 4; ++ni)
      bv[ni] = *(const s16x8*)&Bs_[(wn * 64 + ni * 16 + lr) * BK + lk];
    __builtin_amdgcn_s_setprio(1);
#pragma unroll
    for (int mi = 0; mi < 8; ++mi)
#pragma unroll
      for (int ni = 0; ni < 4; ++ni)
        acc[mi][ni] = mfma16x16x32(av[mi], bv[ni], acc[mi][ni]);
    __builtin_amdgcn_s_setprio(0);
  };

  // prologue: 3 tiles in flight (12 loads/thread)
  STAGE(0); STAGE(1); STAGE(2);

  // main loop: before compute(t), loads newer than tile t = tiles t+1,t+2
  // (8 per thread) -> vmcnt(8) certifies tile t landed; barrier makes that
  // collective. STAGE(t+3) reuses slot (t-1)&3, whose ds_reads completed
  // before every wave crossed this barrier.
  for (int t = 0; t < nkt - 2; ++t) {
    WAITV(8);
    SBAR();
    if (t + 3 < nkt) STAGE(t + 3);
    COMPUTE(t);
  }
  // peeled tail: fewer tiles remain in flight
  WAITV(4);
  SBAR();
  COMPUTE(nkt - 2);
  WAITV(0);
  SBAR();
  COMPUTE(nkt - 1);

  // epilogue: D mapping col=lane&15, row=(lane>>4)*4+j
  const size_t Cbase = (size_t)e * sCe;
  const int row0 = blockIdx.y * BM + wm * 128 + (lane >> 4) * 4;
  const int col0 = blockIdx.x * BN + wn * 64 + lr;
#pragma unroll
  for (int ni = 0; ni < 4; ++ni) {
    const int col = col0 + ni * 16;
    const float bvv = bias ? bias[(size_t)e * sBiasE + col] : 0.f;
#pragma unroll
    for (int mi = 0; mi < 8; ++mi) {
#pragma unroll
      for (int j = 0; j < 4; ++j) {
        float v = acc[mi][ni][j] + bvv;
        if (RELU) v = v > 0.f ? v : 0.f;
        const size_t idx = Cbase + (size_t)(row0 + mi * 16 + j) * ldc + col;
        if (OUTBF16) ((short*)C)[idx] = f2b(v);
        else         ((float*)C)[idx] = v;
      }
    }
  }
}

// ---------------- 128x128 m97 GEMM (kept for GEMM3) ----------------

template <bool RELU, bool OUTBF16>
__global__ __launch_bounds__(256) void gemm_bt_kernel(
    const short* __restrict__ A, const short* __restrict__ Bt, void* __restrict__ C,
    const float* __restrict__ bias, int K, int ldc,
    long sAe, long sBe, long sCe, long sBiasE) {
  constexpr int BM = 128, BN = 128, BK = 32;
  __shared__ short As[BM * BK];
  __shared__ short Bs[BN * BK];
  const int tid  = threadIdx.x;
  const int wid  = tid >> 6;
  const int lane = tid & 63;
  const int e    = blockIdx.z;

  const short* Ap = A + (size_t)e * sAe + (size_t)blockIdx.y * BM * K;
  const short* Bp = Bt + (size_t)e * sBe + (size_t)blockIdx.x * BN * K;

  const int srow = wid * 16 + (lane >> 2);
  const int scol = (lane & 3) * 8;
  const int wm = (wid >> 1) * 64, wn = (wid & 1) * 64;
  const int lr = lane & 15, lk = (lane >> 4) * 8;

  f32x4 acc[4][4] = {};
  const int nkt = K / BK;
  for (int kt = 0; kt < nkt; ++kt) {
    __syncthreads();
    const size_t ko = (size_t)kt * BK;
    GLDS16(Ap + (size_t)srow * K + ko + scol,        &As[wid * 512]);
    GLDS16(Ap + (size_t)(srow + 64) * K + ko + scol, &As[2048 + wid * 512]);
    GLDS16(Bp + (size_t)srow * K + ko + scol,        &Bs[wid * 512]);
    GLDS16(Bp + (size_t)(srow + 64) * K + ko + scol, &Bs[2048 + wid * 512]);
    __syncthreads();

    s16x8 a[4], b[4];
#pragma unroll
    for (int mi = 0; mi < 4; ++mi)
      a[mi] = *(const s16x8*)&As[(wm + mi * 16 + lr) * BK + lk];
#pragma unroll
    for (int ni = 0; ni < 4; ++ni)
      b[ni] = *(const s16x8*)&Bs[(wn + ni * 16 + lr) * BK + lk];
#pragma unroll
    for (int mi = 0; mi < 4; ++mi)
#pragma unroll
      for (int ni = 0; ni < 4; ++ni)
        acc[mi][ni] = mfma16x16x32(a[mi], b[ni], acc[mi][ni]);
  }

  const size_t Cbase = (size_t)e * sCe;
  const int row0 = blockIdx.y * BM + wm + (lane >> 4) * 4;
  const int col0 = blockIdx.x * BN + wn + lr;
#pragma unroll
  for (int ni = 0; ni < 4; ++ni) {
    const int col = col0 + ni * 16;
    const float bv = bias ? bias[(size_t)e * sBiasE + col] : 0.f;
#pragma unroll
    for (int mi = 0; mi < 4; ++mi) {
#pragma unroll
      for (int j = 0; j < 4; ++j) {
        float v = acc[mi][ni][j] + bv;
        if (RELU) v = v > 0.f ? v : 0.f;
        const size_t idx = Cbase + (size_t)(row0 + mi * 16 + j) * ldc + col;
        if (OUTBF16) ((short*)C)[idx] = f2b(v);
        else         ((float*)C)[idx] = v;
      }
    }
  }
}

// ---------------- reduce over experts (per token-chunk) ----------------

__global__ void reduce_y_kernel(const short* __restrict__ yal, const float* __restrict__ b2m,
                                short* __restrict__ ybar, long slab, long total) {
  const size_t base = ((size_t)blockIdx.x * blockDim.x + threadIdx.x) * 8;
  if (base >= (size_t)total) return;
  float s[8] = {};
#pragma unroll
  for (int e = 0; e < N_EXP; ++e) {
    s16x8 v = *(const s16x8*)&yal[(size_t)e * slab + base];
#pragma unroll
    for (int j = 0; j < 8; ++j) s[j] += b2f(v[j]);
  }
  const int col = (int)(base & (D_OUT - 1));
  s16x8 o;
#pragma unroll
  for (int j = 0; j < 8; ++j) o[j] = f2b(s[j] * 0.125f + b2m[col + j]);
  *(s16x8*)&ybar[base] = o;
}

__global__ void tail_kernel(float* __restrict__ out, int from, int n) {
  int i = from + blockIdx.x * blockDim.x + threadIdx.x;
  if (i < n) out[i] = 0.f;
}

// ---------------- launch ----------------

extern "C" void kernel_launch(void* const* d_in, const int* in_sizes, int n_in,
                              void* d_out, int out_size, void* d_ws, size_t ws_size,
                              hipStream_t stream) {
  const float* x  = (const float*)d_in[0];
  const float* W1 = (const float*)d_in[1];
  const float* b1 = (const float*)d_in[2];
  const float* W2 = (const float*)d_in[3];
  const float* b2 = (const float*)d_in[4];
  const float* Wf = (const float*)d_in[5];
  const float* bf = (const float*)d_in[6];
  float* out = (float*)d_out;

  // ---- adaptive chunking: fit fixed + (h+yal)/NC into ws_size ----
  const size_t sz_xb  = (size_t)N_TOK * D_IN * 2;
  const size_t sz_W1t = (size_t)N_EXP * D_HID * D_IN * 2;
  const size_t sz_W2t = (size_t)N_EXP * D_OUT * D_HID * 2;
  const size_t sz_Wft = (size_t)D_OUT * D_OUT * 2;
  const size_t sz_b2m = (size_t)D_OUT * 4;
  const size_t sz_ybr = (size_t)N_TOK * D_OUT * 2;
  const size_t fixed  = sz_xb + sz_W1t + sz_W2t + sz_Wft + sz_b2m + sz_ybr;
  const size_t per_full = (size_t)N_EXP * N_TOK * D_HID * 2   // h
                        + (size_t)N_EXP * N_TOK * D_OUT * 2;  // yal
  int NC = 16;
  for (int c = 1; c <= 8; c <<= 1) {
    if (fixed + per_full / c <= ws_size) { NC = c; break; }
  }
  const int ntokc = N_TOK / NC;

  char* ws = (char*)d_ws;
  short* xb  = (short*)ws; ws += sz_xb;
  short* W1t = (short*)ws; ws += sz_W1t;
  short* W2t = (short*)ws; ws += sz_W2t;
  short* Wft = (short*)ws; ws += sz_Wft;
  float* b2m = (float*)ws; ws += sz_b2m;
  short* ybr = (short*)ws; ws += sz_ybr;
  short* h   = (short*)ws; ws += (size_t)N_EXP * ntokc * D_HID * 2;
  short* yal = (short*)ws;

  // ---- prep: casts + transposes ----
  hipLaunchKernelGGL(cast_x_kernel, dim3(N_TOK * D_IN / 4 / 256), dim3(256), 0, stream,
                     x, xb, N_TOK * D_IN / 4);
  hipLaunchKernelGGL(tcast_kernel, dim3(D_HID / 32, D_IN / 32, N_EXP), dim3(32, 8), 0, stream,
                     W1, W1t, D_IN, D_HID);
  hipLaunchKernelGGL(tcast_kernel, dim3(D_OUT / 32, D_HID / 32, N_EXP), dim3(32, 8), 0, stream,
                     W2, W2t, D_HID, D_OUT);
  hipLaunchKernelGGL(tcast_kernel, dim3(D_OUT / 32, D_OUT / 32, 1), dim3(32, 8), 0, stream,
                     Wf, Wft, D_OUT, D_OUT);
  hipLaunchKernelGGL(b2mean_kernel, dim3(4), dim3(256), 0, stream, b2, b2m);

  const size_t ldsz = 131072;  // 4-slot ring LDS

  // ---- per-token-chunk: GEMM1 -> GEMM2 -> expert-mean ----
  for (int c = 0; c < NC; ++c) {
    const short* xc = xb + (size_t)c * ntokc * D_IN;
    short* ybc = ybr + (size_t)c * ntokc * D_OUT;

    // h[e] = relu(xc @ W1[e] + b1[e])   [ntokc, D_HID] per e
    hipLaunchKernelGGL((gemm256_ring_kernel<true, true>),
                       dim3(D_HID / 256, ntokc / 256, N_EXP), dim3(512), ldsz, stream,
                       xc, W1t, (void*)h, b1, D_IN, D_HID,
                       0L, (long)D_HID * D_IN, (long)ntokc * D_HID, (long)D_HID);

    // yal[e] = h[e] @ W2[e]   [ntokc, D_OUT] per e (bias folded into reduce)
    hipLaunchKernelGGL((gemm256_ring_kernel<false, true>),
                       dim3(D_OUT / 256, ntokc / 256, N_EXP), dim3(512), ldsz, stream,
                       h, W2t, (void*)yal, (const float*)nullptr, D_HID, D_OUT,
                       (long)ntokc * D_HID, (long)D_OUT * D_HID, (long)ntokc * D_OUT, 0L);

    // ybc = mean_e yal + mean_e b2
    hipLaunchKernelGGL(reduce_y_kernel, dim3(ntokc * D_OUT / 8 / 256), dim3(256), 0, stream,
                       yal, b2m, ybc, (long)ntokc * D_OUT, (long)ntokc * D_OUT);
  }

  // ---- out = ybar @ Wf + bf  (fp32 out), 128^2 kernel ----
  hipLaunchKernelGGL((gemm_bt_kernel<false, false>),
                     dim3(D_OUT / 128, N_TOK / 128, 1), dim3(256), 0, stream,
                     ybr, Wft, d_out, bf, D_OUT, D_OUT, 0L, 0L, 0L, 0L);

  // ---- second (scalar) output = 0 ----
  int tail = out_size - N_TOK * D_OUT;
  if (tail > 0)
    hipLaunchKernelGGL(tail_kernel, dim3((tail + 63) / 64), dim3(64), 0, stream,
                       out, N_TOK * D_OUT, out_size);
}